// Round 5
// baseline (835.535 us; speedup 1.0000x reference)
//
#include <hip/hip_runtime.h>
#include <math.h>

#define B_ 8
#define C_ 64
#define W_ 256
#define HWSZ 65536
#define NPIX (B_*HWSZ)        /* 524288 */
#define NELEM (B_*C_*HWSZ)    /* 33554432 */

/* ws layout (float offsets) */
#define WS_H     0
#define WS_SP    33554432
#define WS_STATS 34603008
#define S_SUM    0
#define S_MAXU   512
#define S_GSUM   1024
#define S_GSQ    1088
#define S_CA     1152
#define S_GMEAN  1664
#define S_GRSTD  1728
#define WS_PWT   (WS_STATS + 2048)   /* 12288 floats */

/* LDS tile row stride 24: window-read wave quarters start at banks
   {0,24,16,8} -> every bank exactly 2 lanes = free (m136). Staging now
   WRITES linearly (slot j = LDS addr), skipping pad cols 20-23 -> writes
   also conflict-free. */
#define TSTRIDE 24

typedef float f2v __attribute__((ext_vector_type(2)));

__device__ __forceinline__ float siluf(float v) {
    return v / (1.0f + __expf(-v));
}

__device__ __forceinline__ unsigned fenc(float f) {
    unsigned u = __float_as_uint(f);
    return (u & 0x80000000u) ? ~u : (u | 0x80000000u);
}
__device__ __forceinline__ float fdec(unsigned u) {
    return (u & 0x80000000u) ? __uint_as_float(u & 0x7fffffffu) : __uint_as_float(~u);
}

/* wave64 sum via DPP (VALU pipe, no LDS traffic). Valid in lane 63. */
__device__ __forceinline__ float dpp_sum64(float v) {
    float s = v;
    s += __int_as_float(__builtin_amdgcn_update_dpp(0, __float_as_int(s), 0x111, 0xf, 0xf, false)); /* row_shr:1 */
    s += __int_as_float(__builtin_amdgcn_update_dpp(0, __float_as_int(s), 0x112, 0xf, 0xf, false)); /* row_shr:2 */
    s += __int_as_float(__builtin_amdgcn_update_dpp(0, __float_as_int(s), 0x114, 0xf, 0xf, false)); /* row_shr:4 */
    s += __int_as_float(__builtin_amdgcn_update_dpp(0, __float_as_int(s), 0x118, 0xf, 0xf, false)); /* row_shr:8 */
    s += __int_as_float(__builtin_amdgcn_update_dpp(0, __float_as_int(s), 0x142, 0xf, 0xf, false)); /* row_bcast:15 */
    s += __int_as_float(__builtin_amdgcn_update_dpp(0, __float_as_int(s), 0x143, 0xf, 0xf, false)); /* row_bcast:31 */
    return s;
}

/* wave64 max via DPP. Valid in lane 63. old=self -> fmax identity. */
__device__ __forceinline__ float dpp_max64(float m) {
    int t;
    t = __builtin_amdgcn_update_dpp(__float_as_int(m), __float_as_int(m), 0x111, 0xf, 0xf, false);
    m = fmaxf(m, __int_as_float(t));
    t = __builtin_amdgcn_update_dpp(__float_as_int(m), __float_as_int(m), 0x112, 0xf, 0xf, false);
    m = fmaxf(m, __int_as_float(t));
    t = __builtin_amdgcn_update_dpp(__float_as_int(m), __float_as_int(m), 0x114, 0xf, 0xf, false);
    m = fmaxf(m, __int_as_float(t));
    t = __builtin_amdgcn_update_dpp(__float_as_int(m), __float_as_int(m), 0x118, 0xf, 0xf, false);
    m = fmaxf(m, __int_as_float(t));
    t = __builtin_amdgcn_update_dpp(__float_as_int(m), __float_as_int(m), 0x142, 0xf, 0xf, false);
    m = fmaxf(m, __int_as_float(t));
    t = __builtin_amdgcn_update_dpp(__float_as_int(m), __float_as_int(m), 0x143, 0xf, 0xf, false);
    m = fmaxf(m, __int_as_float(t));
    return m;
}

/* K0: transpose pw_w [64][192] -> pwT [192][64] so K2's uniform loads are contiguous */
__global__ __launch_bounds__(256) void k_tr(const float* __restrict__ pw,
                                            float* __restrict__ pwT) {
    int i = blockIdx.x * 256 + threadIdx.x;
    if (i < 12288) {
        int co = i / 192;
        int k  = i - co * 192;
        pwT[k * 64 + co] = pw[i];
    }
}

/* K1: h = silu(conv1x1(x) + b). Inner product via v_pk_fma_f32:
   2 fp32 FMA / instr, weights broadcast from SGPR pairs. */
__global__ __launch_bounds__(256) void k_conv1(const float* __restrict__ x,
                                               const float* __restrict__ w,
                                               const float* __restrict__ bias,
                                               float* __restrict__ h) {
    int p  = blockIdx.x * 256 + threadIdx.x;
    int b  = p >> 16;
    int hw = p & (HWSZ - 1);
    const float* xp = x + ((size_t)b << 22) + hw;
    f2v xr2[32];
#pragma unroll
    for (int q = 0; q < 32; ++q) {
        f2v t;
        t.x = xp[(size_t)(2 * q) << 16];
        t.y = xp[(size_t)(2 * q + 1) << 16];
        xr2[q] = t;
    }
    float* hp = h + ((size_t)b << 22) + hw;
    const f2v* w2 = (const f2v*)w;            /* row co: f2 idx co*32+q (uniform -> s_load) */
    for (int co = 0; co < 64; ++co) {
        f2v a2;
        a2.x = bias[co]; a2.y = 0.f;
#pragma unroll
        for (int q = 0; q < 32; ++q) {
            f2v wv = w2[co * 32 + q];
            asm("v_pk_fma_f32 %0, %1, %2, %0" : "+v"(a2) : "s"(wv), "v"(xr2[q]));
        }
        hp[(size_t)co << 16] = siluf(a2.x + a2.y);
    }
}

/* K2: fused dw1/dw2/dw3 + pw conv + residual + silus + channel-pool stats.
   Structure identical to the R0/R4 baseline; pw rank-3 update now uses
   v_pk_fma_f32 (96 instr/channel instead of 192 fma), and staging writes
   are LDS-linear (conflict-free both sides). */
__global__ __launch_bounds__(256) void k_msdw(
    const float* __restrict__ h, const float* __restrict__ x,
    const float* __restrict__ dw1w, const float* __restrict__ dw1b,
    const float* __restrict__ dw2w, const float* __restrict__ dw2b,
    const float* __restrict__ dw3w, const float* __restrict__ dw3b,
    const float* __restrict__ pwT, const float* __restrict__ pwb,
    float* __restrict__ hact,
    float* __restrict__ stat_sum, unsigned* __restrict__ stat_max) {
    __shared__ float ht[2][20 * TSTRIDE];     /* 480 slots; cols 20-23 pad, never read */
    __shared__ float red_s[4][64];
    __shared__ float red_m[4][64];
    int tid = threadIdx.x;
    int b   = blockIdx.y;
    int x0  = (blockIdx.x & 15) << 4;
    int y0  = (blockIdx.x >> 4) << 4;
    int tx  = tid & 15, ty = tid >> 4;
    int hw  = ((y0 + ty) << 8) + (x0 + tx);

    /* linear-write staging slots: slot j = LDS word address (2-way, free).
       Pad columns (col>=20) are skipped: garbage slots never read. */
    int j0 = tid;
    int r0 = j0 / 24, c0 = j0 - r0 * 24;
    bool w0 = (c0 < 20);
    int gy0 = y0 - 2 + r0, gx0 = x0 - 2 + c0;
    bool in0 = w0 && ((unsigned)gy0 < 256u) && ((unsigned)gx0 < 256u);
    int off0 = (gy0 << 8) + gx0;
    int j1 = tid + 256;
    int r1 = j1 / 24, c1 = j1 - r1 * 24;
    bool w1 = (j1 < 480) && (c1 < 20);
    int gy1 = y0 - 2 + r1, gx1 = x0 - 2 + c1;
    bool in1 = w1 && ((unsigned)gy1 < 256u) && ((unsigned)gx1 < 256u);
    int off1 = (gy1 << 8) + gx1;

    f2v acc2[32];
#pragma unroll
    for (int i = 0; i < 32; ++i) { acc2[i].x = 0.f; acc2[i].y = 0.f; }

    /* stage c=0 */
    {
        const float* hb = h + ((size_t)(b * 64) << 16);
        if (w0) ht[0][j0] = in0 ? hb[off0] : 0.f;
        if (w1) ht[0][j1] = in1 ? hb[off1] : 0.f;
    }
    __syncthreads();

    const f2v* wp2 = (const f2v*)pwT;         /* [192][64] -> row k at f2 idx k*32 */

    for (int c = 0; c < 64; ++c) {
        int cur = c & 1;
        if (c < 63) {   /* prefetch next channel tile into other buffer */
            const float* hc = h + ((size_t)(b * 64 + c + 1) << 16);
            if (w0) ht[cur ^ 1][j0] = in0 ? hc[off0] : 0.f;
            if (w1) ht[cur ^ 1][j1] = in1 ? hc[off1] : 0.f;
        }
        /* per-channel dw weights: wave-uniform -> scalar regs */
        float w3r[25], w2r[9];
#pragma unroll
        for (int k = 0; k < 25; ++k) w3r[k] = dw3w[c * 25 + k];
#pragma unroll
        for (int k = 0; k < 9; ++k)  w2r[k] = dw2w[c * 9 + k];
        float w1c = dw1w[c], b1c = dw1b[c], b2c = dw2b[c], b3c = dw3b[c];

        float d2 = b2c, d3 = b3c, center = 0.f;
#pragma unroll
        for (int dy = 0; dy < 5; ++dy) {
#pragma unroll
            for (int dx = 0; dx < 5; ++dx) {
                float hv = ht[cur][(ty + dy) * TSTRIDE + tx + dx];
                d3 += hv * w3r[dy * 5 + dx];
                if (dy >= 1 && dy <= 3 && dx >= 1 && dx <= 3)
                    d2 += hv * w2r[(dy - 1) * 3 + (dx - 1)];
                if (dy == 2 && dx == 2) center = hv;
            }
        }
        float d1 = center * w1c + b1c;

        /* pw rank-3 update via packed fp32 FMA: bitwise-identical order per co */
        f2v dd1, dd2, dd3;
        dd1.x = d1; dd1.y = d1;
        dd2.x = d2; dd2.y = d2;
        dd3.x = d3; dd3.y = d3;
        const f2v* wa = wp2 + (c << 5);
        const f2v* wb = wp2 + ((64 + c) << 5);
        const f2v* wc = wp2 + ((128 + c) << 5);
#pragma unroll
        for (int j = 0; j < 32; ++j) {
            f2v va = wa[j], vb = wb[j], vc = wc[j];
            asm("v_pk_fma_f32 %0, %1, %2, %0" : "+v"(acc2[j]) : "s"(va), "v"(dd1));
            asm("v_pk_fma_f32 %0, %1, %2, %0" : "+v"(acc2[j]) : "s"(vb), "v"(dd2));
            asm("v_pk_fma_f32 %0, %1, %2, %0" : "+v"(acc2[j]) : "s"(vc), "v"(dd3));
        }
        __syncthreads();
    }

    /* epilogue: bias+silu, +x, silu, store, pooled sum/max (DPP reduce) */
    int lane = tid & 63, wid = tid >> 6;
    const float* xpix = x + ((size_t)b << 22) + hw;
    float* op = hact + ((size_t)b << 22) + hw;
#pragma unroll
    for (int co = 0; co < 64; ++co) {
        float a = (co & 1) ? acc2[co >> 1].y : acc2[co >> 1].x;
        float v = siluf(a + pwb[co]);
        v += xpix[(size_t)co << 16];
        v = siluf(v);
        op[(size_t)co << 16] = v;
        float S = dpp_sum64(v);
        float M = dpp_max64(v);
        if (lane == 63) { red_s[wid][co] = S; red_m[wid][co] = M; }
    }
    __syncthreads();
    if (tid < 64) {
        float S = red_s[0][tid] + red_s[1][tid] + red_s[2][tid] + red_s[3][tid];
        float M = fmaxf(fmaxf(red_m[0][tid], red_m[1][tid]),
                        fmaxf(red_m[2][tid], red_m[3][tid]));
        atomicAdd(&stat_sum[b * 64 + tid], S);
        atomicMax(&stat_max[b * 64 + tid], fenc(M));
    }
}

/* K3: channel-attention MLP (tiny) */
__global__ __launch_bounds__(64) void k_ca(const float* __restrict__ ssum,
                                           const unsigned* __restrict__ smax,
                                           const float* __restrict__ w1,
                                           const float* __restrict__ w2,
                                           float* __restrict__ ca) {
    __shared__ float avg[64], mxs[64], t1[16];
    int b = blockIdx.x, c = threadIdx.x;
    avg[c] = ssum[b * 64 + c] * (1.0f / 65536.0f);
    mxs[c] = fdec(smax[b * 64 + c]);
    __syncthreads();
    if (c < 16) {
        int j = c & 7;
        const float* src = (c < 8) ? avg : mxs;
        float t = 0.f;
        for (int k = 0; k < 64; ++k) t += w1[j * 64 + k] * src[k];
        t1[c] = fmaxf(t, 0.f);
    }
    __syncthreads();
    float ua = 0.f, um = 0.f;
#pragma unroll
    for (int j = 0; j < 8; ++j) {
        ua += w2[c * 8 + j] * t1[j];
        um += w2[c * 8 + j] * t1[8 + j];
    }
    ca[b * 64 + c] = siluf(ua + um);
}

/* K4a: sp[b][0]=mean_c(ca*h), sp[b][1]=max_c(ca*h)  (4 px / thread) */
__global__ __launch_bounds__(256) void k_spool(const float* __restrict__ hact,
                                               const float* __restrict__ ca,
                                               float* __restrict__ sp) {
    int t  = blockIdx.x * 256 + threadIdx.x;
    int p4 = t << 2;
    int b  = p4 >> 16;             /* pixel index -> batch is >>16 */
    int hw = p4 & (HWSZ - 1);
    const float4* hp = (const float4*)(hact + ((size_t)b << 22) + hw);
    const float*  cab = ca + b * 64;
    float4 mn = {0.f, 0.f, 0.f, 0.f};
    float4 mx = {-3e38f, -3e38f, -3e38f, -3e38f};
#pragma unroll
    for (int c = 0; c < 64; ++c) {
        float cc = cab[c];
        float4 hv = hp[(size_t)c << 14];
        float vx = hv.x * cc, vy = hv.y * cc, vz = hv.z * cc, vw = hv.w * cc;
        mn.x += vx; mn.y += vy; mn.z += vz; mn.w += vw;
        mx.x = fmaxf(mx.x, vx); mx.y = fmaxf(mx.y, vy);
        mx.z = fmaxf(mx.z, vz); mx.w = fmaxf(mx.w, vw);
    }
    mn.x *= (1.f/64.f); mn.y *= (1.f/64.f); mn.z *= (1.f/64.f); mn.w *= (1.f/64.f);
    *(float4*)(sp + ((size_t)(b * 2) << 16) + hw) = mn;
    *(float4*)(sp + ((size_t)(b * 2) << 16) + HWSZ + hw) = mx;
}

/* K4b: sa = silu(conv7x7(sp)); out = sa*ca*h (writes d_out); GN stats */
__global__ __launch_bounds__(256) void k_sattn(const float* __restrict__ hact,
                                               const float* __restrict__ sp,
                                               const float* __restrict__ ca,
                                               const float* __restrict__ saw,
                                               const float* __restrict__ sab,
                                               float* __restrict__ out,
                                               float* __restrict__ gsum,
                                               float* __restrict__ gsq) {
    __shared__ float rs[4][16];
    int tid = threadIdx.x;
    int t   = blockIdx.x * 256 + tid;
    int p4  = t << 2;
    int b   = p4 >> 16;            /* pixel index -> batch is >>16 */
    int hw  = p4 & (HWSZ - 1);
    int y   = hw >> 8, xx = hw & 255;
    float a0 = sab[0], a1 = a0, a2 = a0, a3 = a0;
#pragma unroll
    for (int ch = 0; ch < 2; ++ch) {
        const float* spb = sp + ((size_t)(b * 2 + ch) << 16);
#pragma unroll
        for (int dy = 0; dy < 7; ++dy) {
            int gy = y + dy - 3;
            bool vr = (unsigned)gy < 256u;
            const float* rowp = spb + (gy << 8);
            float r[10];
#pragma unroll
            for (int k = 0; k < 10; ++k) {
                int gx = xx + k - 3;
                r[k] = (vr && (unsigned)gx < 256u) ? rowp[gx] : 0.f;
            }
#pragma unroll
            for (int k = 0; k < 7; ++k) {
                float wv = saw[ch * 49 + dy * 7 + k];
                a0 += r[k] * wv; a1 += r[k+1] * wv; a2 += r[k+2] * wv; a3 += r[k+3] * wv;
            }
        }
    }
    float s0 = siluf(a0), s1 = siluf(a1), s2 = siluf(a2), s3 = siluf(a3);
    const float* cab = ca + b * 64;
    const float4* hp = (const float4*)(hact + ((size_t)b << 22) + hw);
    float4* op = (float4*)(out + ((size_t)b << 22) + hw);
    float gs[8], gq[8];
#pragma unroll
    for (int g = 0; g < 8; ++g) { gs[g] = 0.f; gq[g] = 0.f; }
#pragma unroll
    for (int c = 0; c < 64; ++c) {
        float cc = cab[c];
        float4 hv = hp[(size_t)c << 14];
        float4 o;
        o.x = hv.x * cc * s0; o.y = hv.y * cc * s1;
        o.z = hv.z * cc * s2; o.w = hv.w * cc * s3;
        op[(size_t)c << 14] = o;
        int g = c >> 3;
        gs[g] += o.x + o.y + o.z + o.w;
        gq[g] += o.x*o.x + o.y*o.y + o.z*o.z + o.w*o.w;
    }
    int lane = tid & 63, wid = tid >> 6;
#pragma unroll
    for (int g = 0; g < 8; ++g) {
#pragma unroll
        for (int off = 32; off > 0; off >>= 1) {
            gs[g] += __shfl_xor(gs[g], off);
            gq[g] += __shfl_xor(gq[g], off);
        }
    }
    if (lane == 0) {
#pragma unroll
        for (int g = 0; g < 8; ++g) { rs[wid][g] = gs[g]; rs[wid][8 + g] = gq[g]; }
    }
    __syncthreads();
    if (tid < 16) {
        float v = rs[0][tid] + rs[1][tid] + rs[2][tid] + rs[3][tid];
        int g = tid & 7;
        if (tid < 8) atomicAdd(&gsum[b * 8 + g], v);
        else         atomicAdd(&gsq[b * 8 + g], v);
    }
}

/* K4c: finalize GN stats */
__global__ __launch_bounds__(64) void k_gnstat(const float* __restrict__ gsum,
                                               const float* __restrict__ gsq,
                                               float* __restrict__ gmean,
                                               float* __restrict__ grstd) {
    int t = threadIdx.x;
    const float n = 524288.0f;
    float mu  = gsum[t] / n;
    float var = gsq[t] / n - mu * mu;
    gmean[t] = mu;
    grstd[t] = rsqrtf(var + 1e-5f);
}

/* K5: in-place GroupNorm affine + silu on d_out */
__global__ __launch_bounds__(256) void k_gn(float* __restrict__ out,
                                            const float* __restrict__ gmean,
                                            const float* __restrict__ grstd,
                                            const float* __restrict__ gw,
                                            const float* __restrict__ gb) {
    int t    = blockIdx.x * 256 + threadIdx.x;
    int base = t << 2;
    int c    = (base >> 16) & 63;
    int b    = base >> 22;
    int tg   = b * 8 + (c >> 3);
    float rstd  = grstd[tg];
    float gamma = gw[c] * rstd;
    float beta  = gb[c] - gmean[tg] * gamma;
    float4 v = ((float4*)out)[t];
    v.x = siluf(v.x * gamma + beta);
    v.y = siluf(v.y * gamma + beta);
    v.z = siluf(v.z * gamma + beta);
    v.w = siluf(v.w * gamma + beta);
    ((float4*)out)[t] = v;
}

extern "C" void kernel_launch(void* const* d_in, const int* in_sizes, int n_in,
                              void* d_out, int out_size, void* d_ws, size_t ws_size,
                              hipStream_t stream) {
    const float* x    = (const float*)d_in[0];
    const float* c1w  = (const float*)d_in[1];
    const float* c1b  = (const float*)d_in[2];
    const float* dw1w = (const float*)d_in[3];
    const float* dw1b = (const float*)d_in[4];
    const float* dw2w = (const float*)d_in[5];
    const float* dw2b = (const float*)d_in[6];
    const float* dw3w = (const float*)d_in[7];
    const float* dw3b = (const float*)d_in[8];
    const float* pww  = (const float*)d_in[9];
    const float* pwb  = (const float*)d_in[10];
    const float* caw1 = (const float*)d_in[11];
    const float* caw2 = (const float*)d_in[12];
    const float* saw  = (const float*)d_in[13];
    const float* sab  = (const float*)d_in[14];
    const float* gng  = (const float*)d_in[15];
    const float* gnb  = (const float*)d_in[16];

    float* out   = (float*)d_out;
    float* ws    = (float*)d_ws;
    float* hact  = ws + WS_H;
    float* sp    = ws + WS_SP;
    float* stats = ws + WS_STATS;
    float* ssum  = stats + S_SUM;
    unsigned* smax = (unsigned*)(stats + S_MAXU);
    float* gsum  = stats + S_GSUM;
    float* gsq   = stats + S_GSQ;
    float* cav   = stats + S_CA;
    float* gmean = stats + S_GMEAN;
    float* grstd = stats + S_GRSTD;
    float* pwT   = ws + WS_PWT;

    hipMemsetAsync(stats, 0, 1152 * sizeof(float), stream);
    k_tr<<<48, 256, 0, stream>>>(pww, pwT);
    k_conv1<<<NPIX / 256, 256, 0, stream>>>(x, c1w, c1b, out);
    dim3 g2(256, 8);
    k_msdw<<<g2, 256, 0, stream>>>(out, x, dw1w, dw1b, dw2w, dw2b, dw3w, dw3b,
                                   pwT, pwb, hact, ssum, smax);
    k_ca<<<8, 64, 0, stream>>>(ssum, smax, caw1, caw2, cav);
    k_spool<<<NPIX / 1024, 256, 0, stream>>>(hact, cav, sp);
    k_sattn<<<NPIX / 1024, 256, 0, stream>>>(hact, sp, cav, saw, sab, out, gsum, gsq);
    k_gnstat<<<1, 64, 0, stream>>>(gsum, gsq, gmean, grstd);
    k_gn<<<NELEM / 1024, 256, 0, stream>>>(out, gmean, grstd, gng, gnb);
}